// Round 1
// baseline (417.038 us; speedup 1.0000x reference)
//
#include <hip/hip_runtime.h>
#include <stdint.h>
#include <stddef.h>

#define DIM 1024
#define NEXP 8
#define HID 512
#define NTOK 16384  // 4 * 4096
#define PADK 40     // LDS row pitch in bf16 elems (80B, 16B-aligned, spreads bank quads)

typedef __attribute__((ext_vector_type(4))) float f32x4;
typedef __attribute__((ext_vector_type(8))) short short8;
typedef __attribute__((ext_vector_type(4))) unsigned short u16x4;
typedef __attribute__((ext_vector_type(4))) unsigned int u32x4;

__device__ __forceinline__ unsigned short f2b(float f) {
  unsigned int u = __float_as_uint(f);
  return (unsigned short)((u + 0x7FFFu + ((u >> 16) & 1u)) >> 16);  // RNE
}

__global__ void k_zero(int* __restrict__ counts, int* __restrict__ cursors) {
  int t = threadIdx.x;
  if (t < NEXP) { counts[t] = 0; cursors[t] = 0; }
}

// One wave per token: 8 router dots over D=1024, wave-reduce, argmax (first max).
__global__ __launch_bounds__(256) void k_router(const float* __restrict__ x,
                                                const float* __restrict__ wr,
                                                int* __restrict__ eid,
                                                int* __restrict__ counts) {
  int wid = threadIdx.x >> 6, lane = threadIdx.x & 63;
  int tok = blockIdx.x * 4 + wid;
  if (tok >= NTOK) return;
  const float* xr = x + (size_t)tok * DIM;
  float s[NEXP];
#pragma unroll
  for (int e = 0; e < NEXP; e++) s[e] = 0.f;
  for (int i = 0; i < DIM / 64; i++) {
    float xv = xr[lane + 64 * i];
#pragma unroll
    for (int e = 0; e < NEXP; e++) s[e] += xv * wr[e * DIM + lane + 64 * i];
  }
#pragma unroll
  for (int e = 0; e < NEXP; e++) {
    float v = s[e];
#pragma unroll
    for (int off = 32; off > 0; off >>= 1) v += __shfl_xor(v, off);
    s[e] = v;
  }
  if (lane == 0) {
    int be = 0;
    float bv = s[0];
#pragma unroll
    for (int e = 1; e < NEXP; e++) {
      if (s[e] > bv) { bv = s[e]; be = e; }
    }
    eid[tok] = be;
    atomicAdd(&counts[be], 1);
  }
}

__global__ void k_scan(const int* __restrict__ counts, int* __restrict__ offs) {
  if (threadIdx.x == 0 && blockIdx.x == 0) {
    int a = 0;
    for (int e = 0; e < NEXP; e++) { offs[e] = a; a += counts[e]; }
    offs[NEXP] = a;
  }
}

__global__ void k_scatter(const int* __restrict__ eid, const int* __restrict__ offs,
                          int* __restrict__ cursors, int* __restrict__ tlist) {
  int t = blockIdx.x * blockDim.x + threadIdx.x;
  if (t >= NTOK) return;
  int e = eid[t];
  int pos = atomicAdd(&cursors[e], 1);
  tlist[offs[e] + pos] = t;
}

// Pre-cast both weight tensors fp32 -> bf16 (vectorized).
__global__ __launch_bounds__(256) void k_cast(const float* __restrict__ a,
                                              const float* __restrict__ b,
                                              unsigned short* __restrict__ oa,
                                              unsigned short* __restrict__ ob) {
  const int n4 = NEXP * HID * DIM / 4;
  int stride = gridDim.x * blockDim.x;
  for (int i = blockIdx.x * blockDim.x + threadIdx.x; i < n4; i += stride) {
    f32x4 va = ((const f32x4*)a)[i];
    f32x4 vb = ((const f32x4*)b)[i];
    u16x4 ua, ub;
    ua.x = f2b(va.x); ua.y = f2b(va.y); ua.z = f2b(va.z); ua.w = f2b(va.w);
    ub.x = f2b(vb.x); ub.y = f2b(vb.y); ub.z = f2b(vb.z); ub.w = f2b(vb.w);
    ((u16x4*)oa)[i] = ua;
    ((u16x4*)ob)[i] = ub;
  }
}

// Grouped GEMM, C[m,n] = sum_k A[m,k] * B[n,k]  (both operands K-contiguous).
// IS_FC:  A = x (fp32, gathered by token list, converted to bf16), B = w_fc bf16,
//         epilogue = leaky(0.5)^2 -> bf16 -> hbuf (grouped-dense rows).
// !IS_FC: A = hbuf bf16, B = w_proj bf16, epilogue = fp32 scatter to out[token].
template <int KDIM, int NDIM, bool IS_FC>
__global__ __launch_bounds__(256) void k_gemm(
    const float* __restrict__ x, const unsigned short* __restrict__ hin,
    const unsigned short* __restrict__ wb, const int* __restrict__ offs,
    const int* __restrict__ tlist, unsigned short* __restrict__ hout,
    float* __restrict__ out) {
  int e = blockIdx.z;
  int off = offs[e];
  int me = offs[e + 1] - off;
  int m0 = blockIdx.x * 128;
  if (m0 >= me) return;
  int n0 = blockIdx.y * 128;

  __shared__ unsigned short As[128 * PADK];
  __shared__ unsigned short Bs[128 * PADK];

  int t = threadIdx.x;
  int lane = t & 63, wid = t >> 6;
  int wm = wid >> 1, wn = wid & 1;  // 2x2 waves, each 64x64 output

  f32x4 acc[4][4] = {};

  // staging assignment: 2 threads per tile row (128 rows), each covers 16 K-elems
  int sr = t >> 1;
  int sh = t & 1;
  int agm = m0 + sr;
  if (agm > me - 1) agm = me - 1;  // clamp padding rows (masked at epilogue)
  const float* asrcf = nullptr;
  const unsigned short* asrcb = nullptr;
  if (IS_FC) {
    int tokA = tlist[off + agm];
    asrcf = x + (size_t)tokA * DIM;
  } else {
    asrcb = hin + (size_t)(off + agm) * HID;
  }
  const unsigned short* bsrc = wb + ((size_t)e * NDIM + (n0 + sr)) * (size_t)KDIM;

  for (int kt = 0; kt < KDIM / 32; kt++) {
    __syncthreads();
    int kbase = kt * 32 + sh * 16;
    if (IS_FC) {
#pragma unroll
      for (int i = 0; i < 4; i++) {
        f32x4 v = *(const f32x4*)(asrcf + kbase + 4 * i);
        u16x4 u;
        u.x = f2b(v.x); u.y = f2b(v.y); u.z = f2b(v.z); u.w = f2b(v.w);
        *(u16x4*)&As[sr * PADK + sh * 16 + 4 * i] = u;
      }
    } else {
#pragma unroll
      for (int i = 0; i < 2; i++) {
        u32x4 v = *(const u32x4*)(asrcb + kbase + 8 * i);
        *(u32x4*)&As[sr * PADK + sh * 16 + 8 * i] = v;
      }
    }
#pragma unroll
    for (int i = 0; i < 2; i++) {
      u32x4 v = *(const u32x4*)(bsrc + kbase + 8 * i);
      *(u32x4*)&Bs[sr * PADK + sh * 16 + 8 * i] = v;
    }
    __syncthreads();

    short8 af[4], bfr[4];
#pragma unroll
    for (int i = 0; i < 4; i++) {
      af[i] = *(const short8*)&As[(wm * 64 + i * 16 + (lane & 15)) * PADK + (lane >> 4) * 8];
      bfr[i] = *(const short8*)&Bs[(wn * 64 + i * 16 + (lane & 15)) * PADK + (lane >> 4) * 8];
    }
#pragma unroll
    for (int mi = 0; mi < 4; mi++)
#pragma unroll
      for (int ni = 0; ni < 4; ni++)
        acc[mi][ni] =
            __builtin_amdgcn_mfma_f32_16x16x32_bf16(af[mi], bfr[ni], acc[mi][ni], 0, 0, 0);
  }

  // C/D layout (m89-verified): col = lane&15, row = (lane>>4)*4 + reg
  int rb = (lane >> 4) * 4, cb = lane & 15;
#pragma unroll
  for (int mi = 0; mi < 4; mi++) {
#pragma unroll
    for (int j = 0; j < 4; j++) {
      int ml = wm * 64 + mi * 16 + rb + j;
      if (m0 + ml < me) {
        if (IS_FC) {
#pragma unroll
          for (int ni = 0; ni < 4; ni++) {
            int col = n0 + wn * 64 + ni * 16 + cb;
            float v = acc[mi][ni][j];
            v = (v >= 0.f) ? v * v : 0.25f * v * v;  // leaky(0.5) then square
            hout[(size_t)(off + m0 + ml) * HID + col] = f2b(v);
          }
        } else {
          int tok = tlist[off + m0 + ml];
#pragma unroll
          for (int ni = 0; ni < 4; ni++) {
            int col = n0 + wn * 64 + ni * 16 + cb;
            out[(size_t)tok * DIM + col] = acc[mi][ni][j];
          }
        }
      }
    }
  }
}

extern "C" void kernel_launch(void* const* d_in, const int* in_sizes, int n_in,
                              void* d_out, int out_size, void* d_ws, size_t ws_size,
                              hipStream_t stream) {
  const float* x = (const float*)d_in[0];
  const float* wr = (const float*)d_in[1];
  const float* wfc = (const float*)d_in[2];
  const float* wpj = (const float*)d_in[3];
  float* out = (float*)d_out;

  uintptr_t p = (uintptr_t)d_ws;
  int* counts = (int*)p;   p += 256;
  int* cursors = (int*)p;  p += 256;
  int* offs = (int*)p;     p += 256;
  int* eid = (int*)p;      p += sizeof(int) * NTOK;
  int* tlist = (int*)p;    p += sizeof(int) * NTOK;
  unsigned short* wfc_b = (unsigned short*)p; p += (size_t)NEXP * HID * DIM * 2;
  unsigned short* wpj_b = (unsigned short*)p; p += (size_t)NEXP * DIM * HID * 2;
  unsigned short* hbuf = (unsigned short*)p;  p += (size_t)NTOK * HID * 2;

  k_zero<<<1, 64, 0, stream>>>(counts, cursors);
  k_router<<<NTOK / 4, 256, 0, stream>>>(x, wr, eid, counts);
  k_cast<<<2048, 256, 0, stream>>>(wfc, wpj, wfc_b, wpj_b);
  k_scan<<<1, 1, 0, stream>>>(counts, offs);
  k_scatter<<<NTOK / 256, 256, 0, stream>>>(eid, offs, cursors, tlist);
  // max 128 M-blocks per expert (worst case: all tokens on one expert); idle blocks exit early
  k_gemm<1024, 512, true><<<dim3(128, 4, 8), 256, 0, stream>>>(
      x, nullptr, wfc_b, offs, tlist, hbuf, nullptr);
  k_gemm<512, 1024, false><<<dim3(128, 8, 8), 256, 0, stream>>>(
      nullptr, hbuf, wpj_b, offs, tlist, nullptr, out);
}

// Round 2
// 178.508 us; speedup vs baseline: 2.3362x; 2.3362x over previous
//
#include <hip/hip_runtime.h>
#include <stdint.h>
#include <stddef.h>

#define DIM 1024
#define NEXP 8
#define HID 512
#define NTOK 16384  // 4 * 4096
#define PADK 40     // LDS row pitch in bf16 elems (80B, 16B-aligned)
#define NB_HIST 64  // histogram/scatter blocks (256 tokens each)

typedef __attribute__((ext_vector_type(4))) float f32x4;
typedef __attribute__((ext_vector_type(8))) short short8;
typedef __attribute__((ext_vector_type(4))) unsigned short u16x4;
typedef __attribute__((ext_vector_type(4))) unsigned int u32x4;

__device__ __forceinline__ unsigned short f2b(float f) {
  unsigned int u = __float_as_uint(f);
  return (unsigned short)((u + 0x7FFFu + ((u >> 16) & 1u)) >> 16);  // RNE
}

// One wave per token: 8 router dots over D=1024 (float4 loads), argmax -> eid.
// NO atomics (round-1 lesson: 16384 same-cacheline device atomics = 198us).
__global__ __launch_bounds__(256) void k_router(const float* __restrict__ x,
                                                const float* __restrict__ wr,
                                                int* __restrict__ eid) {
  int wid = threadIdx.x >> 6, lane = threadIdx.x & 63;
  int tok = blockIdx.x * 4 + wid;
  const float* xr = x + (size_t)tok * DIM;
  float s[NEXP];
#pragma unroll
  for (int e = 0; e < NEXP; e++) s[e] = 0.f;
#pragma unroll
  for (int i = 0; i < 4; i++) {
    f32x4 xv = *(const f32x4*)(xr + lane * 4 + 256 * i);
#pragma unroll
    for (int e = 0; e < NEXP; e++) {
      f32x4 wv = *(const f32x4*)(wr + e * DIM + lane * 4 + 256 * i);
      s[e] += xv.x * wv.x + xv.y * wv.y + xv.z * wv.z + xv.w * wv.w;
    }
  }
#pragma unroll
  for (int e = 0; e < NEXP; e++) {
    float v = s[e];
#pragma unroll
    for (int off = 32; off > 0; off >>= 1) v += __shfl_xor(v, off);
    s[e] = v;
  }
  if (lane == 0) {
    int be = 0;
    float bv = s[0];
#pragma unroll
    for (int e = 1; e < NEXP; e++) {
      if (s[e] > bv) { bv = s[e]; be = e; }
    }
    eid[tok] = be;
  }
}

// Per-block histogram of eid via LDS atomics (block-local, cheap).
__global__ __launch_bounds__(256) void k_hist(const int* __restrict__ eid,
                                              int* __restrict__ bc) {
  __shared__ int h[NEXP];
  if (threadIdx.x < NEXP) h[threadIdx.x] = 0;
  __syncthreads();
  int tok = blockIdx.x * (NTOK / NB_HIST) + threadIdx.x;
  atomicAdd(&h[eid[tok]], 1);
  __syncthreads();
  if (threadIdx.x < NEXP) bc[blockIdx.x * NEXP + threadIdx.x] = h[threadIdx.x];
}

// One block: per-expert prefix over NB_HIST blocks, expert offsets, per-block bases.
__global__ void k_scan(const int* __restrict__ bc, int* __restrict__ offs,
                       int* __restrict__ base) {
  __shared__ int cnt[NEXP];
  __shared__ int so[NEXP + 1];
  int t = threadIdx.x;
  if (t < NEXP) {
    int run = 0;
    for (int b = 0; b < NB_HIST; b++) {
      base[b * NEXP + t] = run;
      run += bc[b * NEXP + t];
    }
    cnt[t] = run;
  }
  __syncthreads();
  if (t == 0) {
    int a = 0;
    for (int e = 0; e < NEXP; e++) { so[e] = a; a += cnt[e]; }
    so[NEXP] = a;
  }
  __syncthreads();
  if (t < NEXP + 1) offs[t] = so[t];
  for (int i = t; i < NB_HIST * NEXP; i += blockDim.x) base[i] += so[i % NEXP];
}

// Scatter with LDS cursors seeded from per-block bases. No global atomics.
__global__ __launch_bounds__(256) void k_scatter(const int* __restrict__ eid,
                                                 const int* __restrict__ base,
                                                 int* __restrict__ tlist) {
  __shared__ int cur[NEXP];
  if (threadIdx.x < NEXP) cur[threadIdx.x] = base[blockIdx.x * NEXP + threadIdx.x];
  __syncthreads();
  int tok = blockIdx.x * (NTOK / NB_HIST) + threadIdx.x;
  int e = eid[tok];
  int pos = atomicAdd(&cur[e], 1);
  tlist[pos] = tok;
}

// Pre-cast both weight tensors fp32 -> bf16 (vectorized).
__global__ __launch_bounds__(256) void k_cast(const float* __restrict__ a,
                                              const float* __restrict__ b,
                                              unsigned short* __restrict__ oa,
                                              unsigned short* __restrict__ ob) {
  const int n4 = NEXP * HID * DIM / 4;
  int stride = gridDim.x * blockDim.x;
  for (int i = blockIdx.x * blockDim.x + threadIdx.x; i < n4; i += stride) {
    f32x4 va = ((const f32x4*)a)[i];
    f32x4 vb = ((const f32x4*)b)[i];
    u16x4 ua, ub;
    ua.x = f2b(va.x); ua.y = f2b(va.y); ua.z = f2b(va.z); ua.w = f2b(va.w);
    ub.x = f2b(vb.x); ub.y = f2b(vb.y); ub.z = f2b(vb.z); ub.w = f2b(vb.w);
    ((u16x4*)oa)[i] = ua;
    ((u16x4*)ob)[i] = ub;
  }
}

// Grouped GEMM, C[m,n] = sum_k A[m,k] * B[n,k]  (both operands K-contiguous).
// IS_FC:  A = x (fp32, gathered by token list, converted to bf16), B = w_fc bf16,
//         epilogue = leaky(0.5)^2 -> bf16 -> hbuf (grouped-dense rows).
// !IS_FC: A = hbuf bf16, B = w_proj bf16, epilogue = fp32 scatter to out[token].
template <int KDIM, int NDIM, bool IS_FC>
__global__ __launch_bounds__(256) void k_gemm(
    const float* __restrict__ x, const unsigned short* __restrict__ hin,
    const unsigned short* __restrict__ wb, const int* __restrict__ offs,
    const int* __restrict__ tlist, unsigned short* __restrict__ hout,
    float* __restrict__ out) {
  int e = blockIdx.z;
  int off = offs[e];
  int me = offs[e + 1] - off;
  int m0 = blockIdx.x * 128;
  if (m0 >= me) return;
  int n0 = blockIdx.y * 128;

  __shared__ unsigned short As[128 * PADK];
  __shared__ unsigned short Bs[128 * PADK];

  int t = threadIdx.x;
  int lane = t & 63, wid = t >> 6;
  int wm = wid >> 1, wn = wid & 1;  // 2x2 waves, each 64x64 output

  f32x4 acc[4][4] = {};

  // staging assignment: 2 threads per tile row (128 rows), each covers 16 K-elems
  int sr = t >> 1;
  int sh = t & 1;
  int agm = m0 + sr;
  if (agm > me - 1) agm = me - 1;  // clamp padding rows (masked at epilogue)
  const float* asrcf = nullptr;
  const unsigned short* asrcb = nullptr;
  if (IS_FC) {
    int tokA = tlist[off + agm];
    asrcf = x + (size_t)tokA * DIM;
  } else {
    asrcb = hin + (size_t)(off + agm) * HID;
  }
  const unsigned short* bsrc = wb + ((size_t)e * NDIM + (n0 + sr)) * (size_t)KDIM;

  for (int kt = 0; kt < KDIM / 32; kt++) {
    __syncthreads();
    int kbase = kt * 32 + sh * 16;
    if (IS_FC) {
#pragma unroll
      for (int i = 0; i < 4; i++) {
        f32x4 v = *(const f32x4*)(asrcf + kbase + 4 * i);
        u16x4 u;
        u.x = f2b(v.x); u.y = f2b(v.y); u.z = f2b(v.z); u.w = f2b(v.w);
        *(u16x4*)&As[sr * PADK + sh * 16 + 4 * i] = u;
      }
    } else {
#pragma unroll
      for (int i = 0; i < 2; i++) {
        u32x4 v = *(const u32x4*)(asrcb + kbase + 8 * i);
        *(u32x4*)&As[sr * PADK + sh * 16 + 8 * i] = v;
      }
    }
#pragma unroll
    for (int i = 0; i < 2; i++) {
      u32x4 v = *(const u32x4*)(bsrc + kbase + 8 * i);
      *(u32x4*)&Bs[sr * PADK + sh * 16 + 8 * i] = v;
    }
    __syncthreads();

    short8 af[4], bfr[4];
#pragma unroll
    for (int i = 0; i < 4; i++) {
      af[i] = *(const short8*)&As[(wm * 64 + i * 16 + (lane & 15)) * PADK + (lane >> 4) * 8];
      bfr[i] = *(const short8*)&Bs[(wn * 64 + i * 16 + (lane & 15)) * PADK + (lane >> 4) * 8];
    }
#pragma unroll
    for (int mi = 0; mi < 4; mi++)
#pragma unroll
      for (int ni = 0; ni < 4; ni++)
        acc[mi][ni] =
            __builtin_amdgcn_mfma_f32_16x16x32_bf16(af[mi], bfr[ni], acc[mi][ni], 0, 0, 0);
  }

  // C/D layout (m89-verified): col = lane&15, row = (lane>>4)*4 + reg
  int rb = (lane >> 4) * 4, cb = lane & 15;
#pragma unroll
  for (int mi = 0; mi < 4; mi++) {
#pragma unroll
    for (int j = 0; j < 4; j++) {
      int ml = wm * 64 + mi * 16 + rb + j;
      if (m0 + ml < me) {
        if (IS_FC) {
#pragma unroll
          for (int ni = 0; ni < 4; ni++) {
            int col = n0 + wn * 64 + ni * 16 + cb;
            float v = acc[mi][ni][j];
            v = (v >= 0.f) ? v * v : 0.25f * v * v;  // leaky(0.5) then square
            hout[(size_t)(off + m0 + ml) * HID + col] = f2b(v);
          }
        } else {
          int tok = tlist[off + m0 + ml];
#pragma unroll
          for (int ni = 0; ni < 4; ni++) {
            int col = n0 + wn * 64 + ni * 16 + cb;
            out[(size_t)tok * DIM + col] = acc[mi][ni][j];
          }
        }
      }
    }
  }
}

extern "C" void kernel_launch(void* const* d_in, const int* in_sizes, int n_in,
                              void* d_out, int out_size, void* d_ws, size_t ws_size,
                              hipStream_t stream) {
  const float* x = (const float*)d_in[0];
  const float* wr = (const float*)d_in[1];
  const float* wfc = (const float*)d_in[2];
  const float* wpj = (const float*)d_in[3];
  float* out = (float*)d_out;

  uintptr_t p = (uintptr_t)d_ws;
  int* offs = (int*)p;     p += 256;
  int* bc = (int*)p;       p += sizeof(int) * NB_HIST * NEXP;
  int* base = (int*)p;     p += sizeof(int) * NB_HIST * NEXP;
  int* eid = (int*)p;      p += sizeof(int) * NTOK;
  int* tlist = (int*)p;    p += sizeof(int) * NTOK;
  unsigned short* wfc_b = (unsigned short*)p; p += (size_t)NEXP * HID * DIM * 2;
  unsigned short* wpj_b = (unsigned short*)p; p += (size_t)NEXP * DIM * HID * 2;
  unsigned short* hbuf = (unsigned short*)p;  p += (size_t)NTOK * HID * 2;

  k_router<<<NTOK / 4, 256, 0, stream>>>(x, wr, eid);
  k_cast<<<2048, 256, 0, stream>>>(wfc, wpj, wfc_b, wpj_b);
  k_hist<<<NB_HIST, 256, 0, stream>>>(eid, bc);
  k_scan<<<1, 256, 0, stream>>>(bc, offs, base);
  k_scatter<<<NB_HIST, 256, 0, stream>>>(eid, base, tlist);
  // max 128 M-blocks per expert (worst case: all tokens on one expert); idle blocks exit early
  k_gemm<1024, 512, true><<<dim3(128, 4, 8), 256, 0, stream>>>(
      x, nullptr, wfc_b, offs, tlist, hbuf, nullptr);
  k_gemm<512, 1024, false><<<dim3(128, 8, 8), 256, 0, stream>>>(
      nullptr, hbuf, wpj_b, offs, tlist, nullptr, out);
}

// Round 3
// 134.867 us; speedup vs baseline: 3.0922x; 1.3236x over previous
//
#include <hip/hip_runtime.h>
#include <stdint.h>
#include <stddef.h>

#define DIM 1024
#define NEXP 8
#define HID 512
#define NTOK 16384  // 4 * 4096
#define NB_HIST 64  // histogram/scatter blocks (256 tokens each)

typedef __attribute__((ext_vector_type(4))) float f32x4;
typedef __attribute__((ext_vector_type(8))) short short8;
typedef __attribute__((ext_vector_type(4))) unsigned short u16x4;

__device__ __forceinline__ unsigned short f2b(float f) {
  unsigned int u = __float_as_uint(f);
  return (unsigned short)((u + 0x7FFFu + ((u >> 16) & 1u)) >> 16);  // RNE
}

// 16B async global->LDS. lds ptr must be wave-uniform; HW writes base + lane*16.
__device__ __forceinline__ void gload_lds16(const unsigned short* g, unsigned short* l) {
  __builtin_amdgcn_global_load_lds((const __attribute__((address_space(1))) void*)g,
                                   (__attribute__((address_space(3))) void*)l, 16, 0, 0);
}

// One wave per token: 8 router dots (float4), argmax -> eid. FUSED: writes x as bf16
// (x is streamed here anyway; bf16 x enables global_load_lds staging in the fc GEMM).
__global__ __launch_bounds__(256) void k_router(const float* __restrict__ x,
                                                const float* __restrict__ wr,
                                                int* __restrict__ eid,
                                                unsigned short* __restrict__ xb) {
  int wid = threadIdx.x >> 6, lane = threadIdx.x & 63;
  int tok = blockIdx.x * 4 + wid;
  const float* xr = x + (size_t)tok * DIM;
  unsigned short* xbr = xb + (size_t)tok * DIM;
  float s[NEXP];
#pragma unroll
  for (int e = 0; e < NEXP; e++) s[e] = 0.f;
#pragma unroll
  for (int i = 0; i < 4; i++) {
    f32x4 xv = *(const f32x4*)(xr + lane * 4 + 256 * i);
    u16x4 u;
    u.x = f2b(xv.x); u.y = f2b(xv.y); u.z = f2b(xv.z); u.w = f2b(xv.w);
    *(u16x4*)(xbr + lane * 4 + 256 * i) = u;
#pragma unroll
    for (int e = 0; e < NEXP; e++) {
      f32x4 wv = *(const f32x4*)(wr + e * DIM + lane * 4 + 256 * i);
      s[e] += xv.x * wv.x + xv.y * wv.y + xv.z * wv.z + xv.w * wv.w;
    }
  }
#pragma unroll
  for (int e = 0; e < NEXP; e++) {
    float v = s[e];
#pragma unroll
    for (int off = 32; off > 0; off >>= 1) v += __shfl_xor(v, off);
    s[e] = v;
  }
  if (lane == 0) {
    int be = 0;
    float bv = s[0];
#pragma unroll
    for (int e = 1; e < NEXP; e++) {
      if (s[e] > bv) { bv = s[e]; be = e; }
    }
    eid[tok] = be;
  }
}

// Per-block histogram of eid via LDS atomics.
__global__ __launch_bounds__(256) void k_hist(const int* __restrict__ eid,
                                              int* __restrict__ bc) {
  __shared__ int h[NEXP];
  if (threadIdx.x < NEXP) h[threadIdx.x] = 0;
  __syncthreads();
  int tok = blockIdx.x * (NTOK / NB_HIST) + threadIdx.x;
  atomicAdd(&h[eid[tok]], 1);
  __syncthreads();
  if (threadIdx.x < NEXP) bc[blockIdx.x * NEXP + threadIdx.x] = h[threadIdx.x];
}

// One block: per-expert prefix over blocks, expert offsets, per-block bases.
__global__ void k_scan(const int* __restrict__ bc, int* __restrict__ offs,
                       int* __restrict__ base) {
  __shared__ int cnt[NEXP];
  __shared__ int so[NEXP + 1];
  int t = threadIdx.x;
  if (t < NEXP) {
    int run = 0;
    for (int b = 0; b < NB_HIST; b++) {
      base[b * NEXP + t] = run;
      run += bc[b * NEXP + t];
    }
    cnt[t] = run;
  }
  __syncthreads();
  if (t == 0) {
    int a = 0;
    for (int e = 0; e < NEXP; e++) { so[e] = a; a += cnt[e]; }
    so[NEXP] = a;
  }
  __syncthreads();
  if (t < NEXP + 1) offs[t] = so[t];
  for (int i = t; i < NB_HIST * NEXP; i += blockDim.x) base[i] += so[i % NEXP];
}

// Scatter with LDS cursors seeded from per-block bases. No global atomics.
__global__ __launch_bounds__(256) void k_scatter(const int* __restrict__ eid,
                                                 const int* __restrict__ base,
                                                 int* __restrict__ tlist) {
  __shared__ int cur[NEXP];
  if (threadIdx.x < NEXP) cur[threadIdx.x] = base[blockIdx.x * NEXP + threadIdx.x];
  __syncthreads();
  int tok = blockIdx.x * (NTOK / NB_HIST) + threadIdx.x;
  int e = eid[tok];
  int pos = atomicAdd(&cur[e], 1);
  tlist[pos] = tok;
}

// Pre-cast weight tensors fp32 -> bf16.
__global__ __launch_bounds__(256) void k_cast(const float* __restrict__ a,
                                              const float* __restrict__ b,
                                              unsigned short* __restrict__ oa,
                                              unsigned short* __restrict__ ob) {
  const int n4 = NEXP * HID * DIM / 4;
  int stride = gridDim.x * blockDim.x;
  for (int i = blockIdx.x * blockDim.x + threadIdx.x; i < n4; i += stride) {
    f32x4 va = ((const f32x4*)a)[i];
    f32x4 vb = ((const f32x4*)b)[i];
    u16x4 ua, ub;
    ua.x = f2b(va.x); ua.y = f2b(va.y); ua.z = f2b(va.z); ua.w = f2b(va.w);
    ub.x = f2b(vb.x); ub.y = f2b(vb.y); ub.z = f2b(vb.z); ub.w = f2b(vb.w);
    ((u16x4*)oa)[i] = ua;
    ((u16x4*)ob)[i] = ub;
  }
}

// Grouped GEMM, C[m,n] = sum_k A[m,k]*B[n,k], all bf16 operands, K-contiguous.
// LDS: linear [128][64] tiles, XOR-swizzled chunk index (chunk ^= row&7), fed by
// global_load_lds with INVERSE-swizzled per-lane global source (rule 21: linear
// dest + pre-swizzled source + swizzled read).
// IS_FC:  A = xb gathered by tlist; epilogue leaky(0.5)^2 -> bf16 hbuf.
// !IS_FC: A = hbuf (grouped-dense); epilogue fp32 scatter to out[token].
template <int KDIM, int NDIM, bool IS_FC>
__global__ __launch_bounds__(256) void k_gemm(
    const unsigned short* __restrict__ xb, const unsigned short* __restrict__ hin,
    const unsigned short* __restrict__ wb, const int* __restrict__ offs,
    const int* __restrict__ tlist, unsigned short* __restrict__ hout,
    float* __restrict__ out) {
  int e = blockIdx.z;
  int off = offs[e];
  int me = offs[e + 1] - off;
  int m0 = blockIdx.x * 128;
  if (m0 >= me) return;
  int n0 = blockIdx.y * 128;

  __shared__ unsigned short As[128 * 64];  // 16 KB, row pitch 128B
  __shared__ unsigned short Bs[128 * 64];  // 16 KB

  int t = threadIdx.x;
  int lane = t & 63, w = t >> 6;
  int wm = w >> 1, wn = w & 1;  // 2x2 waves, 64x64 each

  // Staging: issue i covers rows i*32 + w*8 + (lane>>3); lane writes LDS position
  // (lane&7) of its row, which must hold global chunk (lane&7)^(row&7).
  // row&7 == (lane>>3)&7 here, so the source chunk is lane-fixed:
  int srow = w * 8 + (lane >> 3);
  int kb = (lane & 7) ^ ((lane >> 3) & 7);

  const unsigned short* asrc[4];
  const unsigned short* bsrc[4];
#pragma unroll
  for (int i = 0; i < 4; i++) {
    int r = i * 32 + srow;
    int gm = m0 + r;
    if (gm > me - 1) gm = me - 1;  // clamp pad rows (masked at epilogue)
    if (IS_FC) {
      int tok = tlist[off + gm];
      asrc[i] = xb + (size_t)tok * KDIM + kb * 8;
    } else {
      asrc[i] = hin + (size_t)(off + gm) * KDIM + kb * 8;
    }
    bsrc[i] = wb + ((size_t)e * NDIM + n0 + r) * (size_t)KDIM + kb * 8;
  }

  f32x4 acc[4][4] = {};

  for (int kt = 0; kt < KDIM / 64; kt++) {
    __syncthreads();  // previous compute done before overwrite
#pragma unroll
    for (int i = 0; i < 4; i++) {
      gload_lds16(asrc[i] + kt * 64, &As[i * 2048 + w * 512]);
      gload_lds16(bsrc[i] + kt * 64, &Bs[i * 2048 + w * 512]);
    }
    __syncthreads();  // drains vmcnt (compiler emits vmcnt(0) before s_barrier)

#pragma unroll
    for (int ks = 0; ks < 2; ks++) {
      short8 af[4], bf[4];
#pragma unroll
      for (int i = 0; i < 4; i++) {
        int ra = wm * 64 + i * 16 + (lane & 15);
        int ca = (ks * 4 + (lane >> 4)) ^ (ra & 7);
        af[i] = *(const short8*)&As[ra * 64 + ca * 8];
        int rb = wn * 64 + i * 16 + (lane & 15);
        int cb = (ks * 4 + (lane >> 4)) ^ (rb & 7);
        bf[i] = *(const short8*)&Bs[rb * 64 + cb * 8];
      }
#pragma unroll
      for (int mi = 0; mi < 4; mi++)
#pragma unroll
        for (int ni = 0; ni < 4; ni++)
          acc[mi][ni] =
              __builtin_amdgcn_mfma_f32_16x16x32_bf16(af[mi], bf[ni], acc[mi][ni], 0, 0, 0);
    }
  }

  // C/D layout: col = lane&15, row = (lane>>4)*4 + reg
  int rb = (lane >> 4) * 4, cb = lane & 15;
#pragma unroll
  for (int mi = 0; mi < 4; mi++) {
#pragma unroll
    for (int j = 0; j < 4; j++) {
      int ml = wm * 64 + mi * 16 + rb + j;
      if (m0 + ml < me) {
        if (IS_FC) {
#pragma unroll
          for (int ni = 0; ni < 4; ni++) {
            int col = n0 + wn * 64 + ni * 16 + cb;
            float v = acc[mi][ni][j];
            v = (v >= 0.f) ? v * v : 0.25f * v * v;  // leaky(0.5) then square
            hout[(size_t)(off + m0 + ml) * HID + col] = f2b(v);
          }
        } else {
          int tok = tlist[off + m0 + ml];
#pragma unroll
          for (int ni = 0; ni < 4; ni++) {
            int col = n0 + wn * 64 + ni * 16 + cb;
            out[(size_t)tok * DIM + col] = acc[mi][ni][j];
          }
        }
      }
    }
  }
}

extern "C" void kernel_launch(void* const* d_in, const int* in_sizes, int n_in,
                              void* d_out, int out_size, void* d_ws, size_t ws_size,
                              hipStream_t stream) {
  const float* x = (const float*)d_in[0];
  const float* wr = (const float*)d_in[1];
  const float* wfc = (const float*)d_in[2];
  const float* wpj = (const float*)d_in[3];
  float* out = (float*)d_out;

  uintptr_t p = (uintptr_t)d_ws;
  int* offs = (int*)p;  p += 256;
  int* bc = (int*)p;    p += sizeof(int) * NB_HIST * NEXP;
  int* base = (int*)p;  p += sizeof(int) * NB_HIST * NEXP;
  int* eid = (int*)p;   p += sizeof(int) * NTOK;
  int* tlist = (int*)p; p += sizeof(int) * NTOK;
  unsigned short* wfc_b = (unsigned short*)p; p += (size_t)NEXP * HID * DIM * 2;
  unsigned short* wpj_b = (unsigned short*)p; p += (size_t)NEXP * DIM * HID * 2;
  unsigned short* hbuf = (unsigned short*)p;  p += (size_t)NTOK * HID * 2;
  unsigned short* xb = (unsigned short*)p;    p += (size_t)NTOK * DIM * 2;

  k_router<<<NTOK / 4, 256, 0, stream>>>(x, wr, eid, xb);
  k_cast<<<1024, 256, 0, stream>>>(wfc, wpj, wfc_b, wpj_b);
  k_hist<<<NB_HIST, 256, 0, stream>>>(eid, bc);
  k_scan<<<1, 256, 0, stream>>>(bc, offs, base);
  k_scatter<<<NB_HIST, 256, 0, stream>>>(eid, base, tlist);
  k_gemm<1024, 512, true><<<dim3(128, 4, 8), 256, 0, stream>>>(
      xb, nullptr, wfc_b, offs, tlist, hbuf, nullptr);
  k_gemm<512, 1024, false><<<dim3(128, 8, 8), 256, 0, stream>>>(
      nullptr, hbuf, wpj_b, offs, tlist, nullptr, out);
}